// Round 10
// baseline (1188.005 us; speedup 1.0000x reference)
//
#include <hip/hip_runtime.h>
#include <hip/hip_bf16.h>
#include <cstdint>
#include <cstddef>

#define NB      8
#define NPTS    16384
#define NPOINT  128
#define NSAMPLE 32
#define CIN     256
#define CMID    256
#define COUT    256
#define KDIM    259      // 3 + 256
#define KPAD    288      // padded to 9 * 32 for MFMA K-steps
#define XS_STRIDE 296    // bf16 elems; 592B = 37*16 -> 16B-aligned rows
#define HS_STRIDE 264    // bf16 elems; 528B = 33*16 -> 16B-aligned rows

typedef __attribute__((ext_vector_type(8))) short bf16x8;
typedef __attribute__((ext_vector_type(4))) float f32x4;
typedef __attribute__((ext_vector_type(2))) float f32x2;

__device__ __forceinline__ short f2bf(float f) {
  unsigned u = __float_as_uint(f);
  u += 0x7fffu + ((u >> 16) & 1u);
  return (short)(u >> 16);
}

// One DPP max-combine step on a packed u64 (both halves moved with the same
// ctrl, then 64-bit compare-select). CTRL/RMASK are template args because
// __builtin_amdgcn_update_dpp requires integer-constant operands.
template <int CTRL, int RMASK>
__device__ __forceinline__ unsigned long long dpp_umax_step(unsigned long long v) {
  int lo = (int)(unsigned)(v & 0xffffffffull);
  int hi = (int)(unsigned)(v >> 32);
  int nlo = __builtin_amdgcn_update_dpp(lo, lo, CTRL, RMASK, 0xf, false);
  int nhi = __builtin_amdgcn_update_dpp(hi, hi, CTRL, RMASK, 0xf, false);
  unsigned long long o = ((unsigned long long)(unsigned)nhi << 32) | (unsigned)nlo;
  return o > v ? o : v;
}

// ---------------- FPS: FOUR blocks per batch (cross-block argmax) -----------
// Evidence ledger:
//  - r4/r9: pk-f32 (C or asm) never helps; r9 A/B: asm pk = +11us vs r7.
//  - r6: cndmask coord tracking +35% issue, flat. r7 BEST single-block: 229.5
//    (512thr, deferred resolve, DPP reduces), 67% VALU-busy of 2 waves/SIMD.
//  => single-block fps is structurally pinned (~230us, 8 CUs active).
// This round: 4 blocks/batch (32 CUs). Per iteration each block scans 4096
// pts (scan issue /4), reduces locally (r7 DPP chain), then cross-block
// argmax via device-scope atomics on a per-iteration slot:
//   atomicMax(slot[b][it], pack) -> threadfence -> atomicAdd(cnt[b][it],1);
//   all waves spin-acquire cnt==4, load slot, decode winner, read coords
//   from xyz (L2). Fresh slot per iter (zeroed in prep, stream-ordered) ->
//   no reset races. pack = dist(32)|inv_idx(14) with GLOBAL index: the
//   numpy first-max tie rule holds across blocks. Bounded spin converts a
//   (non-expected) co-residency failure into passed:false, not a hang.
#define FPS_K  4                   // blocks per batch
#define FPS_T  512
#define FPS_W  (FPS_T / 64)        // 8 waves
#define FPS_PTS (NPTS / FPS_K)     // 4096 points per block
#define FPS_P  (FPS_PTS / FPS_T)   // 8 points per thread
#define FPS_PH (FPS_P / 2)         // 4 point-pairs per thread

__global__ __launch_bounds__(FPS_T) __attribute__((amdgpu_waves_per_eu(2, 2)))
void fps_kernel(const float* __restrict__ xyz, int* __restrict__ inds,
                unsigned long long* __restrict__ slot, unsigned* __restrict__ cnt) {
#pragma clang fp contract(off)
  const int bk = blockIdx.x;
  const int b = bk >> 2, k = bk & 3;
  const int t = threadIdx.x;
  const int lane = t & 63, w = t >> 6;
  const float* xb = xyz + (size_t)b * NPTS * 3;
  const int base = k * FPS_PTS;
  unsigned long long* sl_b = slot + b * NPOINT;
  unsigned* cn_b = cnt + b * NPOINT;

  f32x2 px[FPS_PH], py[FPS_PH], pz[FPS_PH], dv[FPS_PH];
#pragma unroll
  for (int i = 0; i < FPS_PH; ++i) {
    const int j0 = base + t + (2 * i) * FPS_T;
    const int j1 = j0 + FPS_T;
    px[i] = (f32x2){xb[j0 * 3 + 0], xb[j1 * 3 + 0]};
    py[i] = (f32x2){xb[j0 * 3 + 1], xb[j1 * 3 + 1]};
    pz[i] = (f32x2){xb[j0 * 3 + 2], xb[j1 * 3 + 2]};
    dv[i] = (f32x2){1e10f, 1e10f};
  }
  // Opaque barrier: forbids remat from global; values stay VGPR-resident.
#pragma unroll
  for (int i = 0; i < FPS_PH; ++i) {
    asm volatile("" : "+v"(px[i]), "+v"(py[i]), "+v"(pz[i]), "+v"(dv[i]));
  }

  __shared__ unsigned long long s_pack[2][FPS_W];

  int far = 0;
  float cx = xb[0], cy = xb[1], cz = xb[2];

  for (int it = 0; it < NPOINT; ++it) {
    if (k == 0 && t == 0) inds[b * NPOINT + it] = far;
    const f32x2 vcx = {cx, cx}, vcy = {cy, cy}, vcz = {cz, cz};
    f32x2 best2 = {-1.0f, -1.0f};
    // pass 1: pure math (r7-proven form; scalarizes to exact __f*_rn chain)
#pragma unroll
    for (int i = 0; i < FPS_PH; ++i) {
      f32x2 dx = px[i] - vcx;
      f32x2 dy = py[i] - vcy;
      f32x2 dz = pz[i] - vcz;
      f32x2 d2 = (dx * dx + dy * dy) + dz * dz;
      f32x2 dm = {fminf(dv[i].x, d2.x), fminf(dv[i].y, d2.y)};
      dv[i] = dm;
      best2 = (f32x2){fmaxf(best2.x, dm.x), fmaxf(best2.y, dm.y)};
    }
    const float best = fmaxf(best2.x, best2.y);
    // pass 2: resolve smallest slot attaining best (descending -> smallest
    // assignment lands last; .y before .x so even slot wins within a pair)
    int sl = 0;
#pragma unroll
    for (int i = FPS_PH - 1; i >= 0; --i) {
      if (dv[i].y == best) sl = 2 * i + 1;
      if (dv[i].x == best) sl = 2 * i;
    }
    const int bi = base + t + (sl << 9);  // global point index, 14 bits

    // 46-bit monotone pack: dist(32) | inv_idx(14). dist >= 0 so float-bit
    // order == numeric order; inv_idx makes larger-pack == smaller-index on
    // dist ties (numpy first-max rule), valid ACROSS blocks (global index).
    unsigned long long pk = ((unsigned long long)__float_as_uint(best) << 14)
                          | (unsigned long long)(unsigned)(NPTS - 1 - bi);

    // in-wave max-reduce via DPP; full result in lane 63 -> SGPR broadcast
    pk = dpp_umax_step<0x111, 0xf>(pk);  // row_shr:1
    pk = dpp_umax_step<0x112, 0xf>(pk);  // row_shr:2
    pk = dpp_umax_step<0x114, 0xf>(pk);  // row_shr:4
    pk = dpp_umax_step<0x118, 0xf>(pk);  // row_shr:8
    pk = dpp_umax_step<0x142, 0xa>(pk);  // row_bcast:15 -> rows 1,3
    pk = dpp_umax_step<0x143, 0xc>(pk);  // row_bcast:31 -> rows 2,3
    const unsigned wlo = (unsigned)__builtin_amdgcn_readlane((int)(unsigned)(pk & 0xffffffffull), 63);
    const unsigned whi = (unsigned)__builtin_amdgcn_readlane((int)(unsigned)(pk >> 32), 63);
    const unsigned long long wavepk = ((unsigned long long)whi << 32) | wlo;

    const int par = it & 1;
    if (lane == 0) s_pack[par][w] = wavepk;
    __syncthreads();
    // cross-wave reduce: 8 packs, period-8 across lanes; 3 DPP combine steps
    unsigned long long pm = s_pack[par][lane & 7];
    pm = dpp_umax_step<0x124, 0xf>(pm);  // row_ror:4  (== xor4 on period-8)
    pm = dpp_umax_step<0x4E, 0xf>(pm);   // quad_perm [2,3,0,1] == xor2
    pm = dpp_umax_step<0xB1, 0xf>(pm);   // quad_perm [1,0,3,2] == xor1
    // pm == block winner in all lanes of all waves

    // cross-block argmax: one max+arrival per block; everyone spin-acquires
    if (t == 0) {
      atomicMax(sl_b + it, pm);
      __threadfence();                    // release our max before arrival
      atomicAdd(cn_b + it, 1u);
    }
    unsigned spins = 0;
    while (__hip_atomic_load(cn_b + it, __ATOMIC_ACQUIRE,
                             __HIP_MEMORY_SCOPE_AGENT) < (unsigned)FPS_K) {
      if (++spins > (1u << 20)) break;    // bounded: fail visibly, never hang
    }
    const unsigned long long win = __hip_atomic_load(
        sl_b + it, __ATOMIC_ACQUIRE, __HIP_MEMORY_SCOPE_AGENT);
    far = (NPTS - 1) - (int)(win & (unsigned long long)(NPTS - 1));
    cx = xb[far * 3 + 0]; cy = xb[far * 3 + 1]; cz = xb[far * 3 + 2];
    // no trailing barrier: next iteration's writes use the other parity
  }
}

// ---------------- ball query: one wave per centroid, first-32-in-order ----------
__global__ __launch_bounds__(256) void ballq_kernel(const float* __restrict__ xyz,
                                                    const int* __restrict__ inds,
                                                    int* __restrict__ idx) {
  const int gw   = (blockIdx.x * 256 + threadIdx.x) >> 6;  // 0..1023
  const int lane = threadIdx.x & 63;
  const int b = gw >> 7, s = gw & 127;
  const float* xb = xyz + (size_t)b * NPTS * 3;
  const int ind = inds[b * NPOINT + s];
  const float cx = xb[ind * 3 + 0], cy = xb[ind * 3 + 1], cz = xb[ind * 3 + 2];
  int* o = idx + gw * NSAMPLE;
  const float R2 = (float)(0.4 * 0.4);
  int total = 0;
  int first_hit = 0;
  bool have_first = false;
  for (int base = 0; base < NPTS && total < NSAMPLE; base += 64) {
    const int j = base + lane;
    float dx = __fsub_rn(xb[j * 3 + 0], cx);
    float dy = __fsub_rn(xb[j * 3 + 1], cy);
    float dz = __fsub_rn(xb[j * 3 + 2], cz);
    float d2 = __fadd_rn(__fadd_rn(__fmul_rn(dx, dx), __fmul_rn(dy, dy)), __fmul_rn(dz, dz));
    bool hit = d2 < R2;
    unsigned long long m = __ballot(hit);
    if (!have_first && m) { first_hit = base + (int)__builtin_ctzll(m); have_first = true; }
    int pos = total + (int)__popcll(m & ((1ull << lane) - 1ull));
    if (hit && pos < NSAMPLE) o[pos] = j;
    total += (int)__popcll(m);
  }
  for (int p = total + lane; p < NSAMPLE; p += 64) o[p] = first_hit;  // pad w/ first hit
}

// ---------------- prep: fold BN into bf16 weights + fp32 bias ------------------
// Also zeroes the fps cross-block slot/cnt arrays (stream-ordered before fps,
// re-executed every graph launch).
__global__ __launch_bounds__(256) void prep_kernel(
    const float* __restrict__ w1, const float* __restrict__ g1, const float* __restrict__ be1,
    const float* __restrict__ m1, const float* __restrict__ v1,
    const float* __restrict__ w2, const float* __restrict__ g2, const float* __restrict__ be2,
    const float* __restrict__ m2, const float* __restrict__ v2,
    short* __restrict__ w1b, short* __restrict__ w2b,
    float* __restrict__ b1, float* __restrict__ b2,
    unsigned long long* __restrict__ slot, unsigned* __restrict__ cnt) {
  int i = blockIdx.x * 256 + threadIdx.x;
  if (i < NB * NPOINT) { slot[i] = 0ull; cnt[i] = 0u; }
  if (i < CMID * KPAD) {
    int oc = i / KPAD, c = i - oc * KPAD;
    float a = g1[oc] * rsqrtf(v1[oc] + 1e-5f);
    float val = (c < KDIM) ? w1[oc * KDIM + c] * a : 0.0f;
    w1b[i] = f2bf(val);
    if (c == 0) b1[oc] = be1[oc] - m1[oc] * a;
  }
  if (i < COUT * CMID) {
    int oc = i >> 8, c = i & 255;
    float a = g2[oc] * rsqrtf(v2[oc] + 1e-5f);
    w2b[i] = f2bf(w2[oc * CMID + c] * a);
    if (c == 0) b2[oc] = be2[oc] - m2[oc] * a;
  }
}

// ---------------- fused gather + MLP(2 layers) + maxpool ------------------------
__global__ __launch_bounds__(256) void mlp_kernel(
    const float* __restrict__ xyz, const float* __restrict__ feats,
    const int* __restrict__ inds, const int* __restrict__ idx,
    const short* __restrict__ w1b, const short* __restrict__ w2b,
    const float* __restrict__ b1, const float* __restrict__ b2,
    float* __restrict__ out) {
  const int g   = blockIdx.x;           // b*128 + s
  const int bb  = g >> 7, s = g & 127;
  const int tid = threadIdx.x;
  const int wave = tid >> 6, lane = tid & 63;
  const int lrow = lane & 15, quad = lane >> 4;

  __shared__ short Xs[32 * XS_STRIDE];
  __shared__ short Hs[32 * HS_STRIDE];
  __shared__ int   sj[NSAMPLE];
  __shared__ float scen[3];

  if (tid < NSAMPLE) sj[tid] = idx[g * NSAMPLE + tid];
  if (tid < 3) {
    int ind = inds[bb * NPOINT + s];
    scen[tid] = xyz[((size_t)bb * NPTS + ind) * 3 + tid];
  }
  __syncthreads();

  // gather [32 rows x 288] into LDS as bf16 (pad channels 259..287 = 0)
  for (int e = tid; e < 32 * KPAD; e += 256) {
    int r = e / KPAD, c = e - r * KPAD;
    int j = sj[r];
    float val;
    if (c < 3)          val = xyz[((size_t)bb * NPTS + j) * 3 + c] - scen[c];
    else if (c < KDIM)  val = feats[((size_t)bb * NPTS + j) * CIN + (c - 3)];
    else                val = 0.0f;
    Xs[r * XS_STRIDE + c] = f2bf(val);
  }
  __syncthreads();

  const int nw = wave * 64;   // this wave's output-channel base
  f32x4 acc[4][2];
#pragma unroll
  for (int nt = 0; nt < 4; ++nt)
#pragma unroll
    for (int mt = 0; mt < 2; ++mt) acc[nt][mt] = (f32x4){0.f, 0.f, 0.f, 0.f};

  // GEMM1: [32 x 288] @ W1^T -> [32 x 256]
  for (int ks = 0; ks < 9; ++ks) {
    const int ko = ks * 32 + quad * 8;
    bf16x8 a0 = *(const bf16x8*)(&Xs[lrow * XS_STRIDE + ko]);
    bf16x8 a1 = *(const bf16x8*)(&Xs[(lrow + 16) * XS_STRIDE + ko]);
#pragma unroll
    for (int nt = 0; nt < 4; ++nt) {
      const int oc = nw + nt * 16 + lrow;
      bf16x8 bf = *(const bf16x8*)(w1b + oc * KPAD + ko);
      acc[nt][0] = __builtin_amdgcn_mfma_f32_16x16x32_bf16(a0, bf, acc[nt][0], 0, 0, 0);
      acc[nt][1] = __builtin_amdgcn_mfma_f32_16x16x32_bf16(a1, bf, acc[nt][1], 0, 0, 0);
    }
  }

  // epilogue1: bias + relu -> Hs (bf16). C/D layout: col=lane&15, row=quad*4+reg
#pragma unroll
  for (int nt = 0; nt < 4; ++nt) {
    const int oc = nw + nt * 16 + lrow;
    const float bias = b1[oc];
#pragma unroll
    for (int mt = 0; mt < 2; ++mt) {
#pragma unroll
      for (int r = 0; r < 4; ++r) {
        int row = mt * 16 + quad * 4 + r;
        float h = fmaxf(acc[nt][mt][r] + bias, 0.0f);
        Hs[row * HS_STRIDE + oc] = f2bf(h);
      }
    }
  }
  __syncthreads();

#pragma unroll
  for (int nt = 0; nt < 4; ++nt)
#pragma unroll
    for (int mt = 0; mt < 2; ++mt) acc[nt][mt] = (f32x4){0.f, 0.f, 0.f, 0.f};

  // GEMM2: [32 x 256] @ W2^T -> [32 x 256]
  for (int ks = 0; ks < 8; ++ks) {
    const int ko = ks * 32 + quad * 8;
    bf16x8 a0 = *(const bf16x8*)(&Hs[lrow * HS_STRIDE + ko]);
    bf16x8 a1 = *(const bf16x8*)(&Hs[(lrow + 16) * HS_STRIDE + ko]);
#pragma unroll
    for (int nt = 0; nt < 4; ++nt) {
      const int oc = nw + nt * 16 + lrow;
      bf16x8 bf = *(const bf16x8*)(w2b + oc * CMID + ko);
      acc[nt][0] = __builtin_amdgcn_mfma_f32_16x16x32_bf16(a0, bf, acc[nt][0], 0, 0, 0);
      acc[nt][1] = __builtin_amdgcn_mfma_f32_16x16x32_bf16(a1, bf, acc[nt][1], 0, 0, 0);
    }
  }

  // epilogue2: bias + relu + max over 32 samples -> out[b][oc][s]
#pragma unroll
  for (int nt = 0; nt < 4; ++nt) {
    const int oc = nw + nt * 16 + lrow;
    const float bias = b2[oc];
    float v = -3.4e38f;
#pragma unroll
    for (int mt = 0; mt < 2; ++mt) {
      f32x4 a = acc[nt][mt];
      v = fmaxf(v, fmaxf(fmaxf(a[0], a[1]), fmaxf(a[2], a[3])));
    }
    v = fmaxf(v + bias, 0.0f);            // monotone: == max of per-element bias+relu
    v = fmaxf(v, __shfl_xor(v, 16, 64));
    v = fmaxf(v, __shfl_xor(v, 32, 64));
    if (lane < 16) out[((size_t)bb * COUT + oc) * NPOINT + s] = v;
  }
}

extern "C" void kernel_launch(void* const* d_in, const int* in_sizes, int n_in,
                              void* d_out, int out_size, void* d_ws, size_t ws_size,
                              hipStream_t stream) {
  const float* xyz   = (const float*)d_in[0];
  const float* feats = (const float*)d_in[1];
  const float* w1    = (const float*)d_in[2];
  const float* g1    = (const float*)d_in[3];
  const float* be1   = (const float*)d_in[4];
  const float* m1    = (const float*)d_in[5];
  const float* v1    = (const float*)d_in[6];
  const float* w2    = (const float*)d_in[7];
  const float* g2    = (const float*)d_in[8];
  const float* be2   = (const float*)d_in[9];
  const float* m2    = (const float*)d_in[10];
  const float* v2    = (const float*)d_in[11];
  float* out = (float*)d_out;

  char* ws = (char*)d_ws;
  int*   inds = (int*)(ws);              // 1024 ints   -> 4096 B
  int*   idx  = (int*)(ws + 4096);       // 32768 ints  -> 131072 B
  short* w1b  = (short*)(ws + 135168);   // 256*288 bf16 -> 147456 B
  short* w2b  = (short*)(ws + 282624);   // 256*256 bf16 -> 131072 B
  float* b1   = (float*)(ws + 413696);   // 256 f32
  float* b2   = (float*)(ws + 414720);   // 256 f32
  unsigned long long* slot = (unsigned long long*)(ws + 415744);  // 1024 u64 -> 8192 B
  unsigned* cnt = (unsigned*)(ws + 423936);                       // 1024 u32 -> 4096 B

  prep_kernel<<<288, 256, 0, stream>>>(w1, g1, be1, m1, v1, w2, g2, be2, m2, v2,
                                       w1b, w2b, b1, b2, slot, cnt);
  fps_kernel<<<NB * FPS_K, FPS_T, 0, stream>>>(xyz, inds, slot, cnt);
  ballq_kernel<<<256, 256, 0, stream>>>(xyz, inds, idx);
  mlp_kernel<<<NB * NPOINT, 256, 0, stream>>>(xyz, feats, inds, idx, w1b, w2b, b1, b2, out);
}

// Round 11
// 439.730 us; speedup vs baseline: 2.7017x; 2.7017x over previous
//
#include <hip/hip_runtime.h>
#include <hip/hip_bf16.h>
#include <cstdint>
#include <cstddef>

#define NB      8
#define NPTS    16384
#define NPOINT  128
#define NSAMPLE 32
#define CIN     256
#define CMID    256
#define COUT    256
#define KDIM    259      // 3 + 256
#define KPAD    288      // padded to 9 * 32 for MFMA K-steps
#define XS_STRIDE 296    // bf16 elems; 592B = 37*16 -> 16B-aligned rows
#define HS_STRIDE 264    // bf16 elems; 528B = 33*16 -> 16B-aligned rows

typedef __attribute__((ext_vector_type(8))) short bf16x8;
typedef __attribute__((ext_vector_type(4))) short s16x4;
typedef __attribute__((ext_vector_type(4))) float f32x4;
typedef __attribute__((ext_vector_type(2))) float f32x2;

__device__ __forceinline__ short f2bf(float f) {
  unsigned u = __float_as_uint(f);
  u += 0x7fffu + ((u >> 16) & 1u);
  return (short)(u >> 16);
}

// One DPP max-combine step on a packed u64 (both halves moved with the same
// ctrl, then 64-bit compare-select). CTRL/RMASK are template args because
// __builtin_amdgcn_update_dpp requires integer-constant operands.
template <int CTRL, int RMASK>
__device__ __forceinline__ unsigned long long dpp_umax_step(unsigned long long v) {
  int lo = (int)(unsigned)(v & 0xffffffffull);
  int hi = (int)(unsigned)(v >> 32);
  int nlo = __builtin_amdgcn_update_dpp(lo, lo, CTRL, RMASK, 0xf, false);
  int nhi = __builtin_amdgcn_update_dpp(hi, hi, CTRL, RMASK, 0xf, false);
  unsigned long long o = ((unsigned long long)(unsigned)nhi << 32) | (unsigned)nlo;
  return o > v ? o : v;
}

// ---------------- FPS: one block per batch (r7 exact, measured 229.5us) -----
// Evidence ledger (10 rounds):
//  - r4/r9: pk-f32 (C or asm) never helps (asm pk = +11us A/B vs r7).
//  - r6: cndmask coord tracking +35% issue, flat.
//  - r8: 1024thr/waves_per_eu(4,4): VGPR budget 52 < 64 pinned -> spill, -14%.
//  - r10: 4-block cross-XCD atomic argmax: ~7.5us/iter spin -> 4.2x WORSE.
//  => single-block fps ~229.5us is the structural plateau. Do not touch.
#define FPS_T 512
#define FPS_W (FPS_T / 64)     // 8 waves
#define FPS_P (NPTS / FPS_T)   // 32 points per thread
#define FPS_PH (FPS_P / 2)     // 16 point-pairs per thread

__global__ __launch_bounds__(FPS_T) __attribute__((amdgpu_waves_per_eu(2, 2)))
void fps_kernel(const float* __restrict__ xyz, int* __restrict__ inds) {
#pragma clang fp contract(off)
  const int b = blockIdx.x;
  const int t = threadIdx.x;
  const int lane = t & 63, w = t >> 6;
  const float* xb = xyz + (size_t)b * NPTS * 3;

  f32x2 px[FPS_PH], py[FPS_PH], pz[FPS_PH], dv[FPS_PH];
#pragma unroll
  for (int i = 0; i < FPS_PH; ++i) {
    const int j0 = t + (2 * i) * FPS_T;
    const int j1 = j0 + FPS_T;
    px[i] = (f32x2){xb[j0 * 3 + 0], xb[j1 * 3 + 0]};
    py[i] = (f32x2){xb[j0 * 3 + 1], xb[j1 * 3 + 1]};
    pz[i] = (f32x2){xb[j0 * 3 + 2], xb[j1 * 3 + 2]};
    dv[i] = (f32x2){1e10f, 1e10f};
  }
  // Opaque barrier: values become asm results, so reloading from global is
  // illegal; with the pinned occupancy range they stay register-resident.
#pragma unroll
  for (int i = 0; i < FPS_PH; ++i) {
    asm volatile("" : "+v"(px[i]), "+v"(py[i]), "+v"(pz[i]), "+v"(dv[i]));
  }

  __shared__ unsigned long long s_pack[2][FPS_W];
  __shared__ float swx[2][FPS_W], swy[2][FPS_W], swz[2][FPS_W];

  int far = 0;
  float cx = xb[0], cy = xb[1], cz = xb[2];

  for (int it = 0; it < NPOINT; ++it) {
    if (t == 0) inds[b * NPOINT + it] = far;
    const f32x2 vcx = {cx, cx}, vcy = {cy, cy}, vcz = {cz, cz};
    f32x2 best2 = {-1.0f, -1.0f};
    // pass 1: pure math (scalarizes to the exact __f*_rn chain)
#pragma unroll
    for (int i = 0; i < FPS_PH; ++i) {
      f32x2 dx = px[i] - vcx;
      f32x2 dy = py[i] - vcy;
      f32x2 dz = pz[i] - vcz;
      f32x2 d2 = (dx * dx + dy * dy) + dz * dz;
      f32x2 dm = {fminf(dv[i].x, d2.x), fminf(dv[i].y, d2.y)};
      dv[i] = dm;
      best2 = (f32x2){fmaxf(best2.x, dm.x), fmaxf(best2.y, dm.y)};
    }
    const float best = fmaxf(best2.x, best2.y);
    // pass 2: resolve smallest slot attaining best (descending -> smallest
    // assignment lands last; .y before .x so even slot wins within a pair)
    int sl = 0;
#pragma unroll
    for (int i = FPS_PH - 1; i >= 0; --i) {
      if (dv[i].y == best) sl = 2 * i + 1;
      if (dv[i].x == best) sl = 2 * i;
    }
    const int bi = t + (sl << 9);  // sl * FPS_T; bi & 63 == lane

    // 49-bit monotone pack: dist(32) | inv_idx(14) | wave(3).
    // dist >= 0 so float-bit order == numeric order; inv_idx makes
    // larger-pack == smaller-index on dist ties (numpy first-max rule).
    unsigned long long pk = ((unsigned long long)__float_as_uint(best) << 17)
                          | ((unsigned long long)(unsigned)(NPTS - 1 - bi) << 3)
                          | (unsigned long long)w;

    // in-wave max-reduce via DPP (no LDS latency); full result in lane 63
    pk = dpp_umax_step<0x111, 0xf>(pk);  // row_shr:1
    pk = dpp_umax_step<0x112, 0xf>(pk);  // row_shr:2
    pk = dpp_umax_step<0x114, 0xf>(pk);  // row_shr:4
    pk = dpp_umax_step<0x118, 0xf>(pk);  // row_shr:8
    pk = dpp_umax_step<0x142, 0xa>(pk);  // row_bcast:15 -> rows 1,3
    pk = dpp_umax_step<0x143, 0xc>(pk);  // row_bcast:31 -> rows 2,3
    const unsigned wlo = (unsigned)__builtin_amdgcn_readlane((int)(unsigned)(pk & 0xffffffffull), 63);
    const unsigned whi = (unsigned)__builtin_amdgcn_readlane((int)(unsigned)(pk >> 32), 63);
    const unsigned long long wavepk = ((unsigned long long)whi << 32) | wlo;
    const int wbi = (NPTS - 1) - (int)((wavepk >> 3) & (unsigned long long)(NPTS - 1));

    // winner coords from the owning lane's pinned registers: slot is
    // wave-uniform -> scalar switch (branch tree); owner lane writes LDS.
    const int slot = __builtin_amdgcn_readfirstlane(wbi >> 9);
    float bx = 0.f, by = 0.f, bz = 0.f;
#define CASE_SLOT(k) \
    case (2 * (k)):     bx = px[k].x; by = py[k].x; bz = pz[k].x; break; \
    case (2 * (k) + 1): bx = px[k].y; by = py[k].y; bz = pz[k].y; break;
    switch (slot) {
      CASE_SLOT(0)  CASE_SLOT(1)  CASE_SLOT(2)  CASE_SLOT(3)
      CASE_SLOT(4)  CASE_SLOT(5)  CASE_SLOT(6)  CASE_SLOT(7)
      CASE_SLOT(8)  CASE_SLOT(9)  CASE_SLOT(10) CASE_SLOT(11)
      CASE_SLOT(12) CASE_SLOT(13) CASE_SLOT(14) CASE_SLOT(15)
      default: break;
    }
#undef CASE_SLOT

    const int par = it & 1;
    if (lane == (wbi & 63)) {   // owner lane of the wave winner (unique)
      s_pack[par][w] = wavepk;
      swx[par][w] = bx; swy[par][w] = by; swz[par][w] = bz;
    }
    __syncthreads();
    // cross-wave reduce: 8 packs, period-8 across lanes; 3 DPP combine steps
    unsigned long long pm = s_pack[par][lane & 7];
    pm = dpp_umax_step<0x124, 0xf>(pm);  // row_ror:4  (== xor4 on period-8 data)
    pm = dpp_umax_step<0x4E, 0xf>(pm);   // quad_perm [2,3,0,1] == xor2
    pm = dpp_umax_step<0xB1, 0xf>(pm);   // quad_perm [1,0,3,2] == xor1
    const int wi = (int)(pm & 7ull);
    far = (NPTS - 1) - (int)((pm >> 3) & (unsigned long long)(NPTS - 1));
    cx = swx[par][wi]; cy = swy[par][wi]; cz = swz[par][wi];
    // no trailing barrier: next iteration's leaders write the other parity
  }
}

// ---------------- prep: fold BN into bf16 weights + fp32 bias -------------------
// w1b row layout is PERMUTED for the vectorized mlp gather: position p holds
// original channel (p<256 ? p+3 : p<259 ? p-256 : pad0) -- i.e. feats channels
// first (8B-aligned in Xs), xyz-rel channels at 256..258, zeros to 287.
__global__ __launch_bounds__(256) void prep_kernel(
    const float* __restrict__ w1, const float* __restrict__ g1, const float* __restrict__ be1,
    const float* __restrict__ m1, const float* __restrict__ v1,
    const float* __restrict__ w2, const float* __restrict__ g2, const float* __restrict__ be2,
    const float* __restrict__ m2, const float* __restrict__ v2,
    short* __restrict__ w1b, short* __restrict__ w2b,
    float* __restrict__ b1, float* __restrict__ b2) {
  int i = blockIdx.x * 256 + threadIdx.x;
  if (i < CMID * KPAD) {
    int oc = i / KPAD, p = i - oc * KPAD;
    float a = g1[oc] * rsqrtf(v1[oc] + 1e-5f);
    float val;
    if (p < 256)      val = w1[oc * KDIM + 3 + p] * a;       // feats channel p
    else if (p < KDIM) val = w1[oc * KDIM + (p - 256)] * a;  // xyz channel p-256
    else              val = 0.0f;
    w1b[i] = f2bf(val);
    if (p == 0) b1[oc] = be1[oc] - m1[oc] * a;
  }
  if (i < COUT * CMID) {
    int oc = i >> 8, c = i & 255;
    float a = g2[oc] * rsqrtf(v2[oc] + 1e-5f);
    w2b[i] = f2bf(w2[oc * CMID + c] * a);
    if (c == 0) b2[oc] = be2[oc] - m2[oc] * a;
  }
}

// ---------------- fused ballq + gather + MLP(2 layers) + maxpool ---------------
// Block g == (b,s) == exactly one ball-query centroid. Wave 0 runs the
// verbatim first-32-in-order ballq scan writing sj[] directly in LDS (no idx
// global round-trip, no separate dispatch; straggler centroids only delay
// their own block). Gather is vectorized: feats as float4 (8 loads/thread)
// packed to s16x4 LDS stores; channel order matches the permuted w1b.
__global__ __launch_bounds__(256) void mlp_kernel(
    const float* __restrict__ xyz, const float* __restrict__ feats,
    const int* __restrict__ inds,
    const short* __restrict__ w1b, const short* __restrict__ w2b,
    const float* __restrict__ b1, const float* __restrict__ b2,
    float* __restrict__ out) {
  const int g   = blockIdx.x;           // b*128 + s
  const int bb  = g >> 7, s = g & 127;
  const int tid = threadIdx.x;
  const int wave = tid >> 6, lane = tid & 63;
  const int lrow = lane & 15, quad = lane >> 4;

  __shared__ short Xs[32 * XS_STRIDE];
  __shared__ short Hs[32 * HS_STRIDE];
  __shared__ int   sj[NSAMPLE];

  const float* xb = xyz + (size_t)bb * NPTS * 3;
  const int ind = inds[bb * NPOINT + s];          // same addr all threads
  const float cx = xb[ind * 3 + 0], cy = xb[ind * 3 + 1], cz = xb[ind * 3 + 2];

  // ---- fused ball query (wave 0 only; verbatim first-32-in-order logic) ----
  if (wave == 0) {
    const float R2 = (float)(0.4 * 0.4);
    int total = 0;
    int first_hit = 0;
    bool have_first = false;
    for (int base = 0; base < NPTS && total < NSAMPLE; base += 64) {
      const int j = base + lane;
      float dx = __fsub_rn(xb[j * 3 + 0], cx);
      float dy = __fsub_rn(xb[j * 3 + 1], cy);
      float dz = __fsub_rn(xb[j * 3 + 2], cz);
      float d2 = __fadd_rn(__fadd_rn(__fmul_rn(dx, dx), __fmul_rn(dy, dy)), __fmul_rn(dz, dz));
      bool hit = d2 < R2;
      unsigned long long m = __ballot(hit);
      if (!have_first && m) { first_hit = base + (int)__builtin_ctzll(m); have_first = true; }
      int pos = total + (int)__popcll(m & ((1ull << lane) - 1ull));
      if (hit && pos < NSAMPLE) sj[pos] = j;
      total += (int)__popcll(m);
    }
    for (int p = total + lane; p < NSAMPLE; p += 64) sj[p] = first_hit;
  }
  __syncthreads();

  // ---- gather: feats channels 0..255 as float4 -> s16x4 (8B-aligned) ----
  const float4* f4 = (const float4*)(feats + (size_t)bb * NPTS * CIN);
  for (int u = tid; u < 32 * 64; u += 256) {
    const int r = u >> 6, q = u & 63;
    float4 v = f4[(size_t)sj[r] * 64 + q];
    s16x4 pv = {f2bf(v.x), f2bf(v.y), f2bf(v.z), f2bf(v.w)};
    *(s16x4*)(&Xs[r * XS_STRIDE + 4 * q]) = pv;
  }
  // ---- gather: xyz-rel channels 256..258 + pad 259..287 ----
  for (int u = tid; u < 32 * 32; u += 256) {
    const int r = u >> 5, c = u & 31;   // channel 256+c
    const int j = sj[r];
    float val = 0.0f;
    if (c == 0)      val = xb[j * 3 + 0] - cx;
    else if (c == 1) val = xb[j * 3 + 1] - cy;
    else if (c == 2) val = xb[j * 3 + 2] - cz;
    Xs[r * XS_STRIDE + 256 + c] = f2bf(val);
  }
  __syncthreads();

  const int nw = wave * 64;   // this wave's output-channel base
  f32x4 acc[4][2];
#pragma unroll
  for (int nt = 0; nt < 4; ++nt)
#pragma unroll
    for (int mt = 0; mt < 2; ++mt) acc[nt][mt] = (f32x4){0.f, 0.f, 0.f, 0.f};

  // GEMM1: [32 x 288] @ W1^T -> [32 x 256]  (channel order == permuted w1b)
  for (int ks = 0; ks < 9; ++ks) {
    const int ko = ks * 32 + quad * 8;
    bf16x8 a0 = *(const bf16x8*)(&Xs[lrow * XS_STRIDE + ko]);
    bf16x8 a1 = *(const bf16x8*)(&Xs[(lrow + 16) * XS_STRIDE + ko]);
#pragma unroll
    for (int nt = 0; nt < 4; ++nt) {
      const int oc = nw + nt * 16 + lrow;
      bf16x8 bf = *(const bf16x8*)(w1b + oc * KPAD + ko);
      acc[nt][0] = __builtin_amdgcn_mfma_f32_16x16x32_bf16(a0, bf, acc[nt][0], 0, 0, 0);
      acc[nt][1] = __builtin_amdgcn_mfma_f32_16x16x32_bf16(a1, bf, acc[nt][1], 0, 0, 0);
    }
  }

  // epilogue1: bias + relu -> Hs (bf16). C/D layout: col=lane&15, row=quad*4+reg
#pragma unroll
  for (int nt = 0; nt < 4; ++nt) {
    const int oc = nw + nt * 16 + lrow;
    const float bias = b1[oc];
#pragma unroll
    for (int mt = 0; mt < 2; ++mt) {
#pragma unroll
      for (int r = 0; r < 4; ++r) {
        int row = mt * 16 + quad * 4 + r;
        float h = fmaxf(acc[nt][mt][r] + bias, 0.0f);
        Hs[row * HS_STRIDE + oc] = f2bf(h);
      }
    }
  }
  __syncthreads();

#pragma unroll
  for (int nt = 0; nt < 4; ++nt)
#pragma unroll
    for (int mt = 0; mt < 2; ++mt) acc[nt][mt] = (f32x4){0.f, 0.f, 0.f, 0.f};

  // GEMM2: [32 x 256] @ W2^T -> [32 x 256]
  for (int ks = 0; ks < 8; ++ks) {
    const int ko = ks * 32 + quad * 8;
    bf16x8 a0 = *(const bf16x8*)(&Hs[lrow * HS_STRIDE + ko]);
    bf16x8 a1 = *(const bf16x8*)(&Hs[(lrow + 16) * HS_STRIDE + ko]);
#pragma unroll
    for (int nt = 0; nt < 4; ++nt) {
      const int oc = nw + nt * 16 + lrow;
      bf16x8 bf = *(const bf16x8*)(w2b + oc * CMID + ko);
      acc[nt][0] = __builtin_amdgcn_mfma_f32_16x16x32_bf16(a0, bf, acc[nt][0], 0, 0, 0);
      acc[nt][1] = __builtin_amdgcn_mfma_f32_16x16x32_bf16(a1, bf, acc[nt][1], 0, 0, 0);
    }
  }

  // epilogue2: bias + relu + max over 32 samples -> out[b][oc][s]
#pragma unroll
  for (int nt = 0; nt < 4; ++nt) {
    const int oc = nw + nt * 16 + lrow;
    const float bias = b2[oc];
    float v = -3.4e38f;
#pragma unroll
    for (int mt = 0; mt < 2; ++mt) {
      f32x4 a = acc[nt][mt];
      v = fmaxf(v, fmaxf(fmaxf(a[0], a[1]), fmaxf(a[2], a[3])));
    }
    v = fmaxf(v + bias, 0.0f);            // monotone: == max of per-element bias+relu
    v = fmaxf(v, __shfl_xor(v, 16, 64));
    v = fmaxf(v, __shfl_xor(v, 32, 64));
    if (lane < 16) out[((size_t)bb * COUT + oc) * NPOINT + s] = v;
  }
}

extern "C" void kernel_launch(void* const* d_in, const int* in_sizes, int n_in,
                              void* d_out, int out_size, void* d_ws, size_t ws_size,
                              hipStream_t stream) {
  const float* xyz   = (const float*)d_in[0];
  const float* feats = (const float*)d_in[1];
  const float* w1    = (const float*)d_in[2];
  const float* g1    = (const float*)d_in[3];
  const float* be1   = (const float*)d_in[4];
  const float* m1    = (const float*)d_in[5];
  const float* v1    = (const float*)d_in[6];
  const float* w2    = (const float*)d_in[7];
  const float* g2    = (const float*)d_in[8];
  const float* be2   = (const float*)d_in[9];
  const float* m2    = (const float*)d_in[10];
  const float* v2    = (const float*)d_in[11];
  float* out = (float*)d_out;

  char* ws = (char*)d_ws;
  int*   inds = (int*)(ws);              // 1024 ints   -> 4096 B
  short* w1b  = (short*)(ws + 135168);   // 256*288 bf16 -> 147456 B
  short* w2b  = (short*)(ws + 282624);   // 256*256 bf16 -> 131072 B
  float* b1   = (float*)(ws + 413696);   // 256 f32
  float* b2   = (float*)(ws + 414720);   // 256 f32

  prep_kernel<<<288, 256, 0, stream>>>(w1, g1, be1, m1, v1, w2, g2, be2, m2, v2,
                                       w1b, w2b, b1, b2);
  fps_kernel<<<NB, FPS_T, 0, stream>>>(xyz, inds);
  mlp_kernel<<<NB * NPOINT, 256, 0, stream>>>(xyz, feats, inds, w1b, w2b, b1, b2, out);
}